// Round 7
// baseline (277.677 us; speedup 1.0000x reference)
//
#include <hip/hip_runtime.h>
#include <math.h>

// Fused self-attention, B=8, S=2048, D=64 fp32; outputs context [8,2048,64] and
// full attention filter [8,2048,2048].
//
// Round-13: collapse the dispatch chain 3 -> 2. R12's write-amp fix verified
// (emit2 left the top-5; WRITE_SIZE back to payload). Remaining overhead is
// the serialized launch chain + prep's standalone K/V pass. Changes:
//   - attn_prep deleted. attn_pexp2 now: (a) zeroes its 4 KiB Ctx slice
//     (1024 WGs x one float4/thread); (b) sp==0 WGs build one 64-key VTbf
//     block each (prep's exact V-transpose, kbase=qt*64) ahead of the main
//     loop; (c) K is loaded as f32 and converted to fp16 in-register per tile
//     (identical cast -> identical numerics; K is 4 MiB, L2-resident).
//     Kbf workspace removed entirely.
//   - attn_emit2 identical to R12 (verified: full-granule nt Filt stores, no
//     amplification; relay read in two mappings; loads ahead of stores).
// Structure: pexp2 (QK^T once, p''=2^(s*log2e-4) fp16 relay + partial sums),
// emit2 (no QK^T/exp/LDS; Filt + PV + Ctx atomics over 4 key-splits).

typedef _Float16 f16x8 __attribute__((ext_vector_type(8)));
typedef _Float16 f16x4 __attribute__((ext_vector_type(4)));
typedef float f32x4 __attribute__((ext_vector_type(4)));

#define BATCH 8
#define SDIM 2048
#define DDIM 64
#define KBLK 64
#define NBLK (SDIM / KBLK)      // 32
#define KSPLIT 4
#define BPW (NBLK / KSPLIT)     // 8 key-blocks per WG
#define NROWS (BATCH * SDIM)    // 16384
#define QSCALE 0.180336878f     // 0.125 * log2(e): QK^T result is s*log2e
#define EBIAS 4.0f              // p'' = 2^(acc - 4); cancels in normalization
#define KSTR 72                 // LDS row stride in shorts (144 B, 16B-aligned)

__device__ __forceinline__ float fidx(const float4& v, int i) {
    return ((const float*)&v)[i];
}

// ====== K1: QK^T once -> p'' fp16 relay + partial row sums ======
// Also: Ctx zeroing (all WGs) and VTbf build (sp==0 WGs, one key-block each).
// Swapped MFMA: C[key=quad*4+r][query=col].
__global__ __launch_bounds__(256, 4)
void attn_pexp2(const float* __restrict__ Kg, const float* __restrict__ Qg,
                const float* __restrict__ Vg, const int* __restrict__ Mg,
                short* __restrict__ VTbf, short* __restrict__ Pws,
                float* __restrict__ part, float* __restrict__ Ctx)
{
    __shared__ short VTlds[DDIM][KSTR];

    const int wg = blockIdx.x;
    const int b = wg & 7;
    const int qt = (wg >> 3) & 31;
    const int sp = wg >> 8;
    const int tid = threadIdx.x;
    const int w = tid >> 6, lane = tid & 63, col = lane & 15, quad = lane >> 4;

    // ---- zero this WG's 4 KiB slice of Ctx (4 MiB / 1024 WGs) ----
    {
        f32x4* dst = (f32x4*)Ctx + (size_t)wg * 256;
        dst[tid] = (f32x4){0.f, 0.f, 0.f, 0.f};
    }

    // ---- sp==0 WGs: build VTbf key-block qt for batch b (prep's V code) ----
    if (sp == 0) {
        const int kbase = qt * KBLK;
        const float* Vb = Vg + (size_t)b * SDIM * DDIM;
        {
            const int sv_d0 = (tid & 15) * 4, sv_k0 = (tid >> 4) * 4;
            float4 vreg[4];
            #pragma unroll
            for (int i = 0; i < 4; ++i)
                vreg[i] = *(const float4*)(Vb + (size_t)(kbase + sv_k0 + i) * DDIM + sv_d0);
            #pragma unroll
            for (int dd = 0; dd < 4; ++dd) {
                f16x4 pv;
                pv[0] = (_Float16)fidx(vreg[0], dd);
                pv[1] = (_Float16)fidx(vreg[1], dd);
                pv[2] = (_Float16)fidx(vreg[2], dd);
                pv[3] = (_Float16)fidx(vreg[3], dd);
                *(f16x4*)&VTlds[sv_d0 + dd][sv_k0] = pv;
            }
        }
        __syncthreads();
        {
            const int d = tid >> 2, koff = (tid & 3) * 16;
            f16x8 a = *(const f16x8*)&VTlds[d][koff];
            f16x8 c = *(const f16x8*)&VTlds[d][koff + 8];
            short* dst = VTbf + ((size_t)b * DDIM + d) * SDIM + kbase + koff;
            *(f16x8*)dst = a;
            *(f16x8*)(dst + 8) = c;
        }
    }

    // persistent Q fragment (B operand); 0.125*log2e folded in
    f16x8 aq[2];
    {
        const float* qsrc = Qg + ((size_t)b * SDIM + qt * 64 + w * 16 + col) * DDIM + quad * 8;
        #pragma unroll
        for (int c = 0; c < 2; ++c) {
            float4 f0 = *(const float4*)(qsrc + c * 32);
            float4 f1 = *(const float4*)(qsrc + c * 32 + 4);
            f16x8 a;
            a[0]=(_Float16)(f0.x*QSCALE); a[1]=(_Float16)(f0.y*QSCALE); a[2]=(_Float16)(f0.z*QSCALE); a[3]=(_Float16)(f0.w*QSCALE);
            a[4]=(_Float16)(f1.x*QSCALE); a[5]=(_Float16)(f1.y*QSCALE); a[6]=(_Float16)(f1.z*QSCALE); a[7]=(_Float16)(f1.w*QSCALE);
            aq[c] = a;
        }
    }

    const int kb0 = sp * BPW * KBLK;
    const float* Kfb = Kg + (size_t)b * SDIM * DDIM;
    const int*   Mb = Mg + (size_t)b * SDIM;
    // this lane's P'' row (query = col)
    short* Prow = Pws + ((size_t)b * SDIM + qt * 64 + w * 16 + col) * SDIM;

    float lsum = 0.0f;
    for (int kb = 0; kb < BPW; ++kb) {
        const int kbase = kb0 + kb * KBLK;
        // K fragments: load f32, convert in-register (identical cast to prep's)
        f16x8 kf[4][2];
        #pragma unroll
        for (int t = 0; t < 4; ++t) {
            const float* ksrc = Kfb + (size_t)(kbase + t * 16 + col) * DDIM + quad * 8;
            float4 a0 = *(const float4*)(ksrc);
            float4 a1 = *(const float4*)(ksrc + 4);
            float4 b0 = *(const float4*)(ksrc + 32);
            float4 b1 = *(const float4*)(ksrc + 36);
            f16x8 k0, k1;
            k0[0]=(_Float16)a0.x; k0[1]=(_Float16)a0.y; k0[2]=(_Float16)a0.z; k0[3]=(_Float16)a0.w;
            k0[4]=(_Float16)a1.x; k0[5]=(_Float16)a1.y; k0[6]=(_Float16)a1.z; k0[7]=(_Float16)a1.w;
            k1[0]=(_Float16)b0.x; k1[1]=(_Float16)b0.y; k1[2]=(_Float16)b0.z; k1[3]=(_Float16)b0.w;
            k1[4]=(_Float16)b1.x; k1[5]=(_Float16)b1.y; k1[6]=(_Float16)b1.z; k1[7]=(_Float16)b1.w;
            kf[t][0] = k0;
            kf[t][1] = k1;
        }
        #pragma unroll
        for (int t = 0; t < 4; ++t) {
            f32x4 acc = {0.f, 0.f, 0.f, 0.f};
            acc = __builtin_amdgcn_mfma_f32_16x16x32_f16(kf[t][0], aq[0], acc, 0, 0, 0);
            acc = __builtin_amdgcn_mfma_f32_16x16x32_f16(kf[t][1], aq[1], acc, 0, 0, 0);
            int4 mq = *(const int4*)(Mb + kbase + t * 16 + quad * 4);
            float e0 = mq.x ? 0.0f : exp2f(acc[0] - EBIAS);
            float e1 = mq.y ? 0.0f : exp2f(acc[1] - EBIAS);
            float e2 = mq.z ? 0.0f : exp2f(acc[2] - EBIAS);
            float e3 = mq.w ? 0.0f : exp2f(acc[3] - EBIAS);
            lsum += e0 + e1 + e2 + e3;
            f16x4 pb;
            pb[0] = (_Float16)e0; pb[1] = (_Float16)e1;
            pb[2] = (_Float16)e2; pb[3] = (_Float16)e3;
            // 4 consecutive keys of this query's row -> 8B store (cached relay)
            *(f16x4*)&Prow[kbase + t * 16 + quad * 4] = pb;
        }
    }

    // each lane holds a quarter of this query's keys; sum across quads
    lsum += __shfl_xor(lsum, 16);
    lsum += __shfl_xor(lsum, 32);
    if (quad == 0)
        part[(size_t)sp * NROWS + (size_t)b * SDIM + qt * 64 + w * 16 + col] = lsum;
}

// ======= K2: emit filter + context from the p'' relay (no QK^T, no exp) =======
__global__ __launch_bounds__(256, 4)
void attn_emit2(const short* __restrict__ Pws, const short* __restrict__ VTbf,
                const float* __restrict__ part, float* __restrict__ Ctx,
                float* __restrict__ Filt)
{
    const int wg = blockIdx.x;
    const int b = wg & 7;
    const int qt = (wg >> 3) & 31;
    const int sp = wg >> 8;
    const int tid = threadIdx.x;
    const int w = tid >> 6, lane = tid & 63, col = lane & 15, quad = lane >> 4;

    const short* VTb = VTbf + (size_t)b * DDIM * SDIM;
    float* Ctxb  = Ctx  + (size_t)b * SDIM * DDIM;
    float* Filtb = Filt + (size_t)b * SDIM * SDIM;

    // invl for the Filt row this lane emits (query = col)
    const int qrow_f = qt * 64 + w * 16 + col;
    float invf;
    {
        const size_t row = (size_t)b * SDIM + qrow_f;
        invf = 1.0f / (part[row] + part[NROWS + row] +
                       part[2 * NROWS + row] + part[3 * NROWS + row]);
    }
    // invl for the 4 context rows this lane accumulates (query = quad*4+r)
    float invo[4];
    #pragma unroll
    for (int r = 0; r < 4; ++r) {
        const size_t row = (size_t)b * SDIM + qt * 64 + w * 16 + quad * 4 + r;
        invo[r] = 1.0f / (part[row] + part[NROWS + row] +
                          part[2 * NROWS + row] + part[3 * NROWS + row]);
    }

    const int kb0 = sp * BPW * KBLK;
    const short* Prow = Pws + ((size_t)b * SDIM + qrow_f) * SDIM;

    f32x4 Oacc[4];
    #pragma unroll
    for (int dt = 0; dt < 4; ++dt) Oacc[dt] = (f32x4){0.f, 0.f, 0.f, 0.f};

    for (int kb = 0; kb < BPW; ++kb) {
        const int kbase = kb0 + kb * KBLK;

        // ---- loads first (all ahead of the nt stores, which then stay in
        //      flight: in-order vmcnt never drains them inside the loop) ----
        // store-path mapping (full-granule pattern): keys t*16+quad*4
        f16x4 pp4[4];
        #pragma unroll
        for (int t = 0; t < 4; ++t)
            pp4[t] = *(const f16x4*)&Prow[kbase + t * 16 + quad * 4];
        // PV A-operand mapping: keys c*32+quad*8
        f16x8 pp[2];
        #pragma unroll
        for (int c = 0; c < 2; ++c)
            pp[c] = *(const f16x8*)&Prow[kbase + c * 32 + quad * 8];
        f16x8 vt[2][4];
        #pragma unroll
        for (int c = 0; c < 2; ++c)
            #pragma unroll
            for (int dt = 0; dt < 4; ++dt)
                vt[c][dt] = *(const f16x8*)(VTb + (size_t)(dt * 16 + col) * SDIM + kbase + c * 32 + quad * 8);

        // ---- Filt = f32(p'') * invl; 16 rows x contiguous 64B per instr ----
        #pragma unroll
        for (int t = 0; t < 4; ++t) {
            f32x4 p4;
            p4[0] = (float)pp4[t][0] * invf;
            p4[1] = (float)pp4[t][1] * invf;
            p4[2] = (float)pp4[t][2] * invf;
            p4[3] = (float)pp4[t][3] * invf;
            f32x4* fdst = (f32x4*)&Filtb[(size_t)qrow_f * SDIM + kbase + t * 16 + quad * 4];
            __builtin_nontemporal_store(p4, fdst);
        }

        // ---- O += p'' * V (A-operand straight from relay registers) ----
        #pragma unroll
        for (int c = 0; c < 2; ++c) {
            #pragma unroll
            for (int dt = 0; dt < 4; ++dt)
                Oacc[dt] = __builtin_amdgcn_mfma_f32_16x16x32_f16(pp[c], vt[c][dt], Oacc[dt], 0, 0, 0);
        }
    }

    // accumulate context (scale by this row's invl; 4-way split contention)
    #pragma unroll
    for (int dt = 0; dt < 4; ++dt) {
        #pragma unroll
        for (int r = 0; r < 4; ++r) {
            unsafeAtomicAdd(&Ctxb[(size_t)(qt * 64 + w * 16 + quad * 4 + r) * DDIM + dt * 16 + col],
                            Oacc[dt][r] * invo[r]);
        }
    }
}

extern "C" void kernel_launch(void* const* d_in, const int* in_sizes, int n_in,
                              void* d_out, int out_size, void* d_ws, size_t ws_size,
                              hipStream_t stream) {
    // setup_inputs order: key, query, value, query_attention_mask
    const float* Kg = (const float*)d_in[0];
    const float* Qg = (const float*)d_in[1];
    const float* Vg = (const float*)d_in[2];
    const int*   Mg = (const int*)d_in[3];
    float* Ctx  = (float*)d_out;                                   // [8,2048,64]
    float* Filt = (float*)d_out + (size_t)BATCH * SDIM * DDIM;     // [8,2048,2048]

    // workspace: VTbf 2 MB | part 256 KB | Pws 64 MB
    short* VTbf = (short*)d_ws;                                    // [8][64][2048] fp16
    float* part = (float*)(VTbf + (size_t)BATCH * DDIM * SDIM);    // [4][16384]
    short* Pws  = (short*)(part + (size_t)KSPLIT * NROWS);         // [8][2048][2048] fp16

    // 8 batches x 32 qtiles x 4 key-splits = 1024 WGs (sp = wg>>8 decode)
    attn_pexp2<<<dim3(BATCH * NBLK * KSPLIT), dim3(256), 0, stream>>>(Kg, Qg, Vg, Mg, VTbf, Pws, part, Ctx);
    attn_emit2<<<dim3(BATCH * NBLK * KSPLIT), dim3(256), 0, stream>>>(Pws, VTbf, part, Ctx, Filt);
}

// Round 8
// 253.688 us; speedup vs baseline: 1.0946x; 1.0946x over previous
//
#include <hip/hip_runtime.h>
#include <math.h>

// Fused self-attention, B=8, S=2048, D=64 fp32; outputs context [8,2048,64] and
// full attention filter [8,2048,2048].
//
// Round-14: DRAM-page-locality for both write streams. emit2's write rate was
// ~2-3x below the fill kernel's on the same buffer; per store instruction we
// touched 16 rows 8 KB apart (16 DRAM pages x 64 B). Now both the Filt store
// and the relay store use a transposed mapping: lane stores row
// srow + t*4 + quad at cols col*4.. -> 16 consecutive lanes form one
// contiguous run (256 B f32 / 128 B f16), 4 rows per instruction = 4x fewer
// page touches per byte.
//   - emit2: Filt path re-reads the relay in the transposed mapping (reads
//     are cache-absorbed; only writes need locality); invf becomes invf4[t].
//     PV A-operand read (row=col mapping) unchanged.
//   - pexp2: parks the P'' fragments in the per-wave LDS tile (no barriers),
//     reads back transposed, stores the relay 4-rows-per-instr. Park/read are
//     <=2-way bank conflicts (free on wave64).
// Numerics bit-identical to R13 (same f16 values, same multiply order).
// Structure: 2 kernels; pexp2 (QK^T once, p''=2^(s*log2e-4) relay + sums +
// Ctx zero + VT build), emit2 (Filt + PV + Ctx atomics over 4 key-splits).

typedef _Float16 f16x8 __attribute__((ext_vector_type(8)));
typedef _Float16 f16x4 __attribute__((ext_vector_type(4)));
typedef float f32x4 __attribute__((ext_vector_type(4)));

#define BATCH 8
#define SDIM 2048
#define DDIM 64
#define KBLK 64
#define NBLK (SDIM / KBLK)      // 32
#define KSPLIT 4
#define BPW (NBLK / KSPLIT)     // 8 key-blocks per WG
#define NROWS (BATCH * SDIM)    // 16384
#define QSCALE 0.180336878f     // 0.125 * log2(e): QK^T result is s*log2e
#define EBIAS 4.0f              // p'' = 2^(acc - 4); cancels in normalization
#define KSTR 72                 // LDS row stride in shorts (144 B, 16B-aligned)

__device__ __forceinline__ float fidx(const float4& v, int i) {
    return ((const float*)&v)[i];
}

// ====== K1: QK^T once -> p'' fp16 relay + partial row sums ======
// Also: Ctx zeroing (all WGs) and VTbf build (sp==0 WGs, one key-block each).
// Swapped MFMA: C[key=quad*4+r][query=col].
__global__ __launch_bounds__(256, 4)
void attn_pexp2(const float* __restrict__ Kg, const float* __restrict__ Qg,
                const float* __restrict__ Vg, const int* __restrict__ Mg,
                short* __restrict__ VTbf, short* __restrict__ Pws,
                float* __restrict__ part, float* __restrict__ Ctx)
{
    __shared__ short VTlds[DDIM][KSTR];
    __shared__ short Plds[4][16][KSTR];   // per-wave P'' tile [q=16][k=64]

    const int wg = blockIdx.x;
    const int b = wg & 7;
    const int qt = (wg >> 3) & 31;
    const int sp = wg >> 8;
    const int tid = threadIdx.x;
    const int w = tid >> 6, lane = tid & 63, col = lane & 15, quad = lane >> 4;
    const int srow = qt * 64 + w * 16;

    // ---- zero this WG's 4 KiB slice of Ctx (4 MiB / 1024 WGs) ----
    {
        f32x4* dst = (f32x4*)Ctx + (size_t)wg * 256;
        dst[tid] = (f32x4){0.f, 0.f, 0.f, 0.f};
    }

    // ---- sp==0 WGs: build VTbf key-block qt for batch b ----
    if (sp == 0) {
        const int kbase = qt * KBLK;
        const float* Vb = Vg + (size_t)b * SDIM * DDIM;
        {
            const int sv_d0 = (tid & 15) * 4, sv_k0 = (tid >> 4) * 4;
            float4 vreg[4];
            #pragma unroll
            for (int i = 0; i < 4; ++i)
                vreg[i] = *(const float4*)(Vb + (size_t)(kbase + sv_k0 + i) * DDIM + sv_d0);
            #pragma unroll
            for (int dd = 0; dd < 4; ++dd) {
                f16x4 pv;
                pv[0] = (_Float16)fidx(vreg[0], dd);
                pv[1] = (_Float16)fidx(vreg[1], dd);
                pv[2] = (_Float16)fidx(vreg[2], dd);
                pv[3] = (_Float16)fidx(vreg[3], dd);
                *(f16x4*)&VTlds[sv_d0 + dd][sv_k0] = pv;
            }
        }
        __syncthreads();
        {
            const int d = tid >> 2, koff = (tid & 3) * 16;
            f16x8 a = *(const f16x8*)&VTlds[d][koff];
            f16x8 c = *(const f16x8*)&VTlds[d][koff + 8];
            short* dst = VTbf + ((size_t)b * DDIM + d) * SDIM + kbase + koff;
            *(f16x8*)dst = a;
            *(f16x8*)(dst + 8) = c;
        }
    }

    // persistent Q fragment (B operand); 0.125*log2e folded in
    f16x8 aq[2];
    {
        const float* qsrc = Qg + ((size_t)b * SDIM + srow + col) * DDIM + quad * 8;
        #pragma unroll
        for (int c = 0; c < 2; ++c) {
            float4 f0 = *(const float4*)(qsrc + c * 32);
            float4 f1 = *(const float4*)(qsrc + c * 32 + 4);
            f16x8 a;
            a[0]=(_Float16)(f0.x*QSCALE); a[1]=(_Float16)(f0.y*QSCALE); a[2]=(_Float16)(f0.z*QSCALE); a[3]=(_Float16)(f0.w*QSCALE);
            a[4]=(_Float16)(f1.x*QSCALE); a[5]=(_Float16)(f1.y*QSCALE); a[6]=(_Float16)(f1.z*QSCALE); a[7]=(_Float16)(f1.w*QSCALE);
            aq[c] = a;
        }
    }

    const int kb0 = sp * BPW * KBLK;
    const float* Kfb = Kg + (size_t)b * SDIM * DDIM;
    const int*   Mb = Mg + (size_t)b * SDIM;

    float lsum = 0.0f;
    for (int kb = 0; kb < BPW; ++kb) {
        const int kbase = kb0 + kb * KBLK;
        // K fragments: load f32, convert in-register
        f16x8 kf[4][2];
        #pragma unroll
        for (int t = 0; t < 4; ++t) {
            const float* ksrc = Kfb + (size_t)(kbase + t * 16 + col) * DDIM + quad * 8;
            float4 a0 = *(const float4*)(ksrc);
            float4 a1 = *(const float4*)(ksrc + 4);
            float4 b0 = *(const float4*)(ksrc + 32);
            float4 b1 = *(const float4*)(ksrc + 36);
            f16x8 k0, k1;
            k0[0]=(_Float16)a0.x; k0[1]=(_Float16)a0.y; k0[2]=(_Float16)a0.z; k0[3]=(_Float16)a0.w;
            k0[4]=(_Float16)a1.x; k0[5]=(_Float16)a1.y; k0[6]=(_Float16)a1.z; k0[7]=(_Float16)a1.w;
            k1[0]=(_Float16)b0.x; k1[1]=(_Float16)b0.y; k1[2]=(_Float16)b0.z; k1[3]=(_Float16)b0.w;
            k1[4]=(_Float16)b1.x; k1[5]=(_Float16)b1.y; k1[6]=(_Float16)b1.z; k1[7]=(_Float16)b1.w;
            kf[t][0] = k0;
            kf[t][1] = k1;
        }
        #pragma unroll
        for (int t = 0; t < 4; ++t) {
            f32x4 acc = {0.f, 0.f, 0.f, 0.f};
            acc = __builtin_amdgcn_mfma_f32_16x16x32_f16(kf[t][0], aq[0], acc, 0, 0, 0);
            acc = __builtin_amdgcn_mfma_f32_16x16x32_f16(kf[t][1], aq[1], acc, 0, 0, 0);
            int4 mq = *(const int4*)(Mb + kbase + t * 16 + quad * 4);
            float e0 = mq.x ? 0.0f : exp2f(acc[0] - EBIAS);
            float e1 = mq.y ? 0.0f : exp2f(acc[1] - EBIAS);
            float e2 = mq.z ? 0.0f : exp2f(acc[2] - EBIAS);
            float e3 = mq.w ? 0.0f : exp2f(acc[3] - EBIAS);
            lsum += e0 + e1 + e2 + e3;
            f16x4 pb;
            pb[0] = (_Float16)e0; pb[1] = (_Float16)e1;
            pb[2] = (_Float16)e2; pb[3] = (_Float16)e3;
            // park in the per-wave LDS tile (row = this lane's query = col)
            *(f16x4*)&Plds[w][col][t * 16 + quad * 4] = pb;
        }
        // transposed relay store: lane -> row t*4+quad, keys col*4..col*4+3
        // => per instruction: 4 rows x (16 lanes x 8B = 128B contiguous)
        #pragma unroll
        for (int t = 0; t < 4; ++t) {
            f16x4 pr = *(const f16x4*)&Plds[w][t * 4 + quad][col * 4];
            *(f16x4*)&Pws[((size_t)b * SDIM + srow + t * 4 + quad) * SDIM + kbase + col * 4] = pr;
        }
    }

    // each lane holds a quarter of this query's keys; sum across quads
    lsum += __shfl_xor(lsum, 16);
    lsum += __shfl_xor(lsum, 32);
    if (quad == 0)
        part[(size_t)sp * NROWS + (size_t)b * SDIM + srow + col] = lsum;
}

// ======= K2: emit filter + context from the p'' relay (no QK^T, no exp) =======
__global__ __launch_bounds__(256, 4)
void attn_emit2(const short* __restrict__ Pws, const short* __restrict__ VTbf,
                const float* __restrict__ part, float* __restrict__ Ctx,
                float* __restrict__ Filt)
{
    const int wg = blockIdx.x;
    const int b = wg & 7;
    const int qt = (wg >> 3) & 31;
    const int sp = wg >> 8;
    const int tid = threadIdx.x;
    const int w = tid >> 6, lane = tid & 63, col = lane & 15, quad = lane >> 4;
    const int srow = qt * 64 + w * 16;

    const short* VTb = VTbf + (size_t)b * DDIM * SDIM;
    float* Ctxb  = Ctx  + (size_t)b * SDIM * DDIM;
    float* Filtb = Filt + (size_t)b * SDIM * SDIM;

    // invf4[t]: 1/l for the Filt-store rows srow + t*4 + quad
    float invf4[4];
    #pragma unroll
    for (int t = 0; t < 4; ++t) {
        const size_t row = (size_t)b * SDIM + srow + t * 4 + quad;
        invf4[t] = 1.0f / (part[row] + part[NROWS + row] +
                           part[2 * NROWS + row] + part[3 * NROWS + row]);
    }
    // invo[r]: 1/l for the Ctx rows srow + quad*4 + r
    float invo[4];
    #pragma unroll
    for (int r = 0; r < 4; ++r) {
        const size_t row = (size_t)b * SDIM + srow + quad * 4 + r;
        invo[r] = 1.0f / (part[row] + part[NROWS + row] +
                          part[2 * NROWS + row] + part[3 * NROWS + row]);
    }

    const int kb0 = sp * BPW * KBLK;
    const short* Prow = Pws + ((size_t)b * SDIM + srow + col) * SDIM;   // PV mapping

    f32x4 Oacc[4];
    #pragma unroll
    for (int dt = 0; dt < 4; ++dt) Oacc[dt] = (f32x4){0.f, 0.f, 0.f, 0.f};

    for (int kb = 0; kb < BPW; ++kb) {
        const int kbase = kb0 + kb * KBLK;

        // ---- loads first (all ahead of the nt stores; in-order vmcnt never
        //      drains the stores inside the loop) ----
        // store-path relay read, transposed mapping: row srow+t*4+quad
        f16x4 pv4[4];
        #pragma unroll
        for (int t = 0; t < 4; ++t)
            pv4[t] = *(const f16x4*)&Pws[((size_t)b * SDIM + srow + t * 4 + quad) * SDIM + kbase + col * 4];
        // PV A-operand mapping (row = this lane's query = col)
        f16x8 pp[2];
        #pragma unroll
        for (int c = 0; c < 2; ++c)
            pp[c] = *(const f16x8*)&Prow[kbase + c * 32 + quad * 8];
        f16x8 vt[2][4];
        #pragma unroll
        for (int c = 0; c < 2; ++c)
            #pragma unroll
            for (int dt = 0; dt < 4; ++dt)
                vt[c][dt] = *(const f16x8*)(VTb + (size_t)(dt * 16 + col) * SDIM + kbase + c * 32 + quad * 8);

        // ---- Filt = f32(p'') * invl; transposed mapping:
        //      per instruction 4 rows x (16 lanes x 16B = 256B contiguous) ----
        #pragma unroll
        for (int t = 0; t < 4; ++t) {
            f32x4 p4;
            p4[0] = (float)pv4[t][0] * invf4[t];
            p4[1] = (float)pv4[t][1] * invf4[t];
            p4[2] = (float)pv4[t][2] * invf4[t];
            p4[3] = (float)pv4[t][3] * invf4[t];
            f32x4* fdst = (f32x4*)&Filtb[(size_t)(srow + t * 4 + quad) * SDIM + kbase + col * 4];
            __builtin_nontemporal_store(p4, fdst);
        }

        // ---- O += p'' * V (A-operand straight from relay registers) ----
        #pragma unroll
        for (int c = 0; c < 2; ++c) {
            #pragma unroll
            for (int dt = 0; dt < 4; ++dt)
                Oacc[dt] = __builtin_amdgcn_mfma_f32_16x16x32_f16(pp[c], vt[c][dt], Oacc[dt], 0, 0, 0);
        }
    }

    // accumulate context (scale by this row's invl; 4-way split contention)
    #pragma unroll
    for (int dt = 0; dt < 4; ++dt) {
        #pragma unroll
        for (int r = 0; r < 4; ++r) {
            unsafeAtomicAdd(&Ctxb[(size_t)(srow + quad * 4 + r) * DDIM + dt * 16 + col],
                            Oacc[dt][r] * invo[r]);
        }
    }
}

extern "C" void kernel_launch(void* const* d_in, const int* in_sizes, int n_in,
                              void* d_out, int out_size, void* d_ws, size_t ws_size,
                              hipStream_t stream) {
    // setup_inputs order: key, query, value, query_attention_mask
    const float* Kg = (const float*)d_in[0];
    const float* Qg = (const float*)d_in[1];
    const float* Vg = (const float*)d_in[2];
    const int*   Mg = (const int*)d_in[3];
    float* Ctx  = (float*)d_out;                                   // [8,2048,64]
    float* Filt = (float*)d_out + (size_t)BATCH * SDIM * DDIM;     // [8,2048,2048]

    // workspace: VTbf 2 MB | part 256 KB | Pws 64 MB
    short* VTbf = (short*)d_ws;                                    // [8][64][2048] fp16
    float* part = (float*)(VTbf + (size_t)BATCH * DDIM * SDIM);    // [4][16384]
    short* Pws  = (short*)(part + (size_t)KSPLIT * NROWS);         // [8][2048][2048] fp16

    // 8 batches x 32 qtiles x 4 key-splits = 1024 WGs (sp = wg>>8 decode)
    attn_pexp2<<<dim3(BATCH * NBLK * KSPLIT), dim3(256), 0, stream>>>(Kg, Qg, Vg, Mg, VTbf, Pws, part, Ctx);
    attn_emit2<<<dim3(BATCH * NBLK * KSPLIT), dim3(256), 0, stream>>>(Pws, VTbf, part, Ctx, Filt);
}